// Round 11
// baseline (168.365 us; speedup 1.0000x reference)
//
#include <hip/hip_runtime.h>
#include <math.h>

#define NCLS 100
#define D 64
#define GACC_FLOATS (NCLS * D * 2 + NCLS)   // 12900: sums[6400] sq[6400] cnt[100]
#define G1 768         // seg blocks (3 per CU)
#define BLK 256
#define PBLK 12800     // per-block partial floats: sums[6400] sq[6400]
#define SUPF 4096      // super-tile floats: 64 rows x 64 cols (16 KB)

typedef __attribute__((ext_vector_type(8)))  short bf16x8;
typedef __attribute__((ext_vector_type(16))) float f32x16;
typedef __attribute__((ext_vector_type(2)))  float f32x2;
typedef __attribute__((ext_vector_type(4)))  int   i32x4;

#define ZV16 {0.f,0.f,0.f,0.f,0.f,0.f,0.f,0.f,0.f,0.f,0.f,0.f,0.f,0.f,0.f,0.f}

union B8 { uint32_t u[4]; bf16x8 v; };

// packed f32->bf16 RNE; used for BOTH A and B so pair-order convention cancels
__device__ __forceinline__ uint32_t cvtpk(float lo, float hi) {
    uint32_t r;
    asm("v_cvt_pk_bf16_f32 %0, %1, %2" : "=v"(r) : "v"(lo), "v"(hi));
    return r;
}

__device__ __forceinline__ void global_fadd(float* p, float v) {
    asm volatile("global_atomic_add_f32 %0, %1, off"
                 :: "v"((uint64_t)(uintptr_t)p), "v"(v));
}

__device__ __forceinline__ void lds_fadd(uint32_t byteoff, float v) {
    asm volatile("ds_add_f32 %0, %1" :: "v"(byteoff), "v"(v));
}

// stage one 64x64 f32 super-tile (16 KB) into LDS, linear layout. 4 gll/wave.
__device__ __forceinline__ void stage_super(const float* __restrict__ pred, size_t st,
                                            float* sb, int w, int lane) {
    const float* src = pred + st * SUPF;
    #pragma unroll
    for (int r = 0; r < 4; ++r) {
        int c = r * 4 + w;                       // 16 chunks of 256 floats
        const float* gs = src + (size_t)c * 256 + (size_t)lane * 4;
        float* ls = sb + c * 256;
        __builtin_amdgcn_global_load_lds(
            (const __attribute__((address_space(1))) uint32_t*)gs,
            (__attribute__((address_space(3))) uint32_t*)ls, 16, 0, 0);
    }
}

// scalar idx load: 16 ints (one iter's k-range) as 4 SGPR quads
#define IDX_SLOAD(q0_, q1_, q2_, q3_, IT)                                      \
    { uint64_t ib_ = ibase + (uint64_t)((IT) * 64);                            \
      asm volatile("s_load_dwordx4 %0, %1, 0"  : "=&s"(q0_) : "s"(ib_));       \
      asm volatile("s_load_dwordx4 %0, %1, 16" : "=&s"(q1_) : "s"(ib_));       \
      asm volatile("s_load_dwordx4 %0, %1, 32" : "=&s"(q2_) : "s"(ib_));       \
      asm volatile("s_load_dwordx4 %0, %1, 48" : "=&s"(q3_) : "s"(ib_)); }

// ---------------- Kernel 1: segmented sum/sumsq via one-hot MFMA ----------
// Wave w: classes [32w,32w+32). A: row=lane&31(class), k=(lane>>5)*8+e.
// B: col=lane&31, same k. C/D: col=lane&31, row=(reg&3)+8*(reg>>2)+4*(lane>>5).
// [fragment conventions validated R3-R10, absmax ~3e-4]
// Counted-vmcnt pipeline (T3/T4): raw s_barrier, vmcnt(4) NOT 0 in main loop.
// idx on the SCALAR path (s_load_dwordx4, prefetched 1 iter ahead) - removes
// idx gll + 2 ds_read_b128/iter (~27% of DS-unit cycles, the R10 co-limiter).
__global__ __launch_bounds__(BLK, 3) void seg_mfma_kernel(
    const float* __restrict__ pred, const int* __restrict__ idx,
    float* __restrict__ part, float* __restrict__ gacc,
    int nrows, int atomicPath)
{
    __shared__ float sbuf[2][SUPF];              // 2 x 16 KB

    const int bid   = blockIdx.x;
    const int tid   = threadIdx.x;
    const int lane  = tid & 63;
    const int w     = tid >> 6;
    const int col   = lane & 31;
    const int kg    = lane >> 5;
    const int mycls = w * 32 + col;

    f32x16 aS0 = ZV16, aS1 = ZV16, aQ0 = ZV16, aQ1 = ZV16;

    const size_t nst = (size_t)nrows >> 6;       // full 64-row super-tiles
    const size_t st0 = (size_t)bid * nst / G1;
    const size_t st1 = ((size_t)bid + 1) * nst / G1;

    if (st0 < st1) {
        stage_super(pred, st0, sbuf[0], w, lane);

        int cur = 0;
        for (size_t st = st0; st < st1; ++st) {
            const uint64_t ibase = (uint64_t)(uintptr_t)(idx + st * 64);

            if (st + 1 < st1)
                stage_super(pred, st + 1, sbuf[cur ^ 1], w, lane);

            // prime iter0 scalars (latency hidden under the vmcnt wait)
            i32x4 ca0, ca1, ca2, ca3;
            IDX_SLOAD(ca0, ca1, ca2, ca3, 0)

            if (st + 1 < st1) {
                asm volatile("s_waitcnt vmcnt(4)" ::: "memory");   // stage(st) landed; st+1 in flight
            } else {
                asm volatile("s_waitcnt vmcnt(0)" ::: "memory");
            }
            __builtin_amdgcn_sched_barrier(0);
            __builtin_amdgcn_s_barrier();        // RAW: every wave's stage(st) chunk landed

            const uint32_t sb32 = (uint32_t)(uintptr_t)&sbuf[cur][0];
            i32x4 na0, na1, na2, na3;

#define ITER_BODY(MT, KK, Q0_, Q1_, Q2_, Q3_, PF_NEXT, NIT)                          \
            {                                                                        \
                if (PF_NEXT) IDX_SLOAD(na0, na1, na2, na3, NIT)                      \
                const int rowk = (MT) * 32 + (KK) * 16 + kg * 8;                     \
                const uint32_t b0 = sb32 + (uint32_t)(rowk * 256) + (uint32_t)col * 4; \
                f32x2 p0, p1, p2, p3, p4, p5, p6, p7;                                \
                asm volatile("ds_read2_b32 %0, %1 offset0:0 offset1:64"     : "=v"(p0) : "v"(b0)); \
                asm volatile("ds_read2_b32 %0, %1 offset0:128 offset1:192"  : "=v"(p1) : "v"(b0)); \
                asm volatile("ds_read2_b32 %0, %1 offset0:0 offset1:64"     : "=v"(p2) : "v"(b0 + 1024u)); \
                asm volatile("ds_read2_b32 %0, %1 offset0:128 offset1:192"  : "=v"(p3) : "v"(b0 + 1024u)); \
                asm volatile("ds_read2_b32 %0, %1 offset0:0 offset1:64"     : "=v"(p4) : "v"(b0 + 128u)); \
                asm volatile("ds_read2_b32 %0, %1 offset0:128 offset1:192"  : "=v"(p5) : "v"(b0 + 128u)); \
                asm volatile("ds_read2_b32 %0, %1 offset0:0 offset1:64"     : "=v"(p6) : "v"(b0 + 1152u)); \
                asm volatile("ds_read2_b32 %0, %1 offset0:128 offset1:192"  : "=v"(p7) : "v"(b0 + 1152u)); \
                asm volatile("s_waitcnt lgkmcnt(0)" ::: "memory");                   \
                __builtin_amdgcn_sched_barrier(0);               /* rule #18 */      \
                int e0 = kg ? Q2_.x : Q0_.x;  int e1 = kg ? Q2_.y : Q0_.y;           \
                int e2 = kg ? Q2_.z : Q0_.z;  int e3 = kg ? Q2_.w : Q0_.w;           \
                int e4 = kg ? Q3_.x : Q1_.x;  int e5 = kg ? Q3_.y : Q1_.y;           \
                int e6 = kg ? Q3_.z : Q1_.z;  int e7 = kg ? Q3_.w : Q1_.w;           \
                B8 ab;                                                               \
                ab.u[0] = cvtpk(e0==mycls?1.f:0.f, e1==mycls?1.f:0.f);               \
                ab.u[1] = cvtpk(e2==mycls?1.f:0.f, e3==mycls?1.f:0.f);               \
                ab.u[2] = cvtpk(e4==mycls?1.f:0.f, e5==mycls?1.f:0.f);               \
                ab.u[3] = cvtpk(e6==mycls?1.f:0.f, e7==mycls?1.f:0.f);               \
                B8 bv, bq;                                                           \
                bv.u[0] = cvtpk(p0.x, p0.y);  bq.u[0] = cvtpk(p0.x*p0.x, p0.y*p0.y); \
                bv.u[1] = cvtpk(p1.x, p1.y);  bq.u[1] = cvtpk(p1.x*p1.x, p1.y*p1.y); \
                bv.u[2] = cvtpk(p2.x, p2.y);  bq.u[2] = cvtpk(p2.x*p2.x, p2.y*p2.y); \
                bv.u[3] = cvtpk(p3.x, p3.y);  bq.u[3] = cvtpk(p3.x*p3.x, p3.y*p3.y); \
                aS0 = __builtin_amdgcn_mfma_f32_32x32x16_bf16(ab.v, bv.v, aS0, 0, 0, 0); \
                aQ0 = __builtin_amdgcn_mfma_f32_32x32x16_bf16(ab.v, bq.v, aQ0, 0, 0, 0); \
                bv.u[0] = cvtpk(p4.x, p4.y);  bq.u[0] = cvtpk(p4.x*p4.x, p4.y*p4.y); \
                bv.u[1] = cvtpk(p5.x, p5.y);  bq.u[1] = cvtpk(p5.x*p5.x, p5.y*p5.y); \
                bv.u[2] = cvtpk(p6.x, p6.y);  bq.u[2] = cvtpk(p6.x*p6.x, p6.y*p6.y); \
                bv.u[3] = cvtpk(p7.x, p7.y);  bq.u[3] = cvtpk(p7.x*p7.x, p7.y*p7.y); \
                aS1 = __builtin_amdgcn_mfma_f32_32x32x16_bf16(ab.v, bv.v, aS1, 0, 0, 0); \
                aQ1 = __builtin_amdgcn_mfma_f32_32x32x16_bf16(ab.v, bq.v, aQ1, 0, 0, 0); \
            }

            ITER_BODY(0, 0, ca0, ca1, ca2, ca3, 1, 1)
            ITER_BODY(0, 1, na0, na1, na2, na3, 0, 0)
            { i32x4 t0=na0, t1=na1, t2=na2, t3=na3;   // rotate before reuse
              IDX_SLOAD(na0, na1, na2, na3, 2)
              ca0=t0; ca1=t1; ca2=t2; ca3=t3; }
            ITER_BODY(1, 0, na0, na1, na2, na3, 0, 0)
            { IDX_SLOAD(ca0, ca1, ca2, ca3, 3) }
            ITER_BODY(1, 1, ca0, ca1, ca2, ca3, 0, 0)
#undef ITER_BODY

            __builtin_amdgcn_s_barrier();        // WAR: all waves done reading buf[cur]
            cur ^= 1;
        }
    }

    // tail rows (nrows % 64), block 0, masked direct loads
    if (bid == 0 && (nrows & 63)) {
        for (size_t base = nst * 64; base < (size_t)nrows; base += 16) {
            int c[8]; float v0[8], v1[8];
            #pragma unroll
            for (int e = 0; e < 8; ++e) {
                size_t kk = base + (size_t)kg * 8 + e;
                bool ok = kk < (size_t)nrows;
                c[e]  = ok ? idx[kk] : -1;
                v0[e] = ok ? pred[kk * 64 + col] : 0.0f;
                v1[e] = ok ? pred[kk * 64 + 32 + col] : 0.0f;
            }
            B8 ab, b0, q0, b1, q1;
            #pragma unroll
            for (int e = 0; e < 4; ++e) {
                ab.u[e] = cvtpk(c[2*e]==mycls?1.f:0.f, c[2*e+1]==mycls?1.f:0.f);
                b0.u[e] = cvtpk(v0[2*e],          v0[2*e+1]);
                q0.u[e] = cvtpk(v0[2*e]*v0[2*e],  v0[2*e+1]*v0[2*e+1]);
                b1.u[e] = cvtpk(v1[2*e],          v1[2*e+1]);
                q1.u[e] = cvtpk(v1[2*e]*v1[2*e],  v1[2*e+1]*v1[2*e+1]);
            }
            aS0 = __builtin_amdgcn_mfma_f32_32x32x16_bf16(ab.v, b0.v, aS0, 0, 0, 0);
            aQ0 = __builtin_amdgcn_mfma_f32_32x32x16_bf16(ab.v, q0.v, aQ0, 0, 0, 0);
            aS1 = __builtin_amdgcn_mfma_f32_32x32x16_bf16(ab.v, b1.v, aS1, 0, 0, 0);
            aQ1 = __builtin_amdgcn_mfma_f32_32x32x16_bf16(ab.v, q1.v, aQ1, 0, 0, 0);
        }
    }

    // epilogue: coalesced per-block partials (or atomic fallback)
    if (!atomicPath) {
        float* pp = part + (size_t)bid * PBLK;
        #pragma unroll
        for (int reg = 0; reg < 16; ++reg) {
            int row = (reg & 3) + 8 * (reg >> 2) + 4 * kg;
            int gm  = w * 32 + row;
            if (gm < NCLS) {
                pp[gm * 64 + col]              = aS0[reg];
                pp[gm * 64 + 32 + col]         = aS1[reg];
                pp[6400 + gm * 64 + col]       = aQ0[reg];
                pp[6400 + gm * 64 + 32 + col]  = aQ1[reg];
            }
        }
    } else {
        #pragma unroll
        for (int reg = 0; reg < 16; ++reg) {
            int row = (reg & 3) + 8 * (reg >> 2) + 4 * kg;
            int gm  = w * 32 + row;
            if (gm < NCLS) {
                global_fadd(&gacc[gm * 64 + col],             aS0[reg]);
                global_fadd(&gacc[gm * 64 + 32 + col],        aS1[reg]);
                global_fadd(&gacc[6400 + gm * 64 + col],      aQ0[reg]);
                global_fadd(&gacc[6400 + gm * 64 + 32 + col], aQ1[reg]);
            }
        }
    }
}

// ---------------- Kernel 1b: standalone hist (atomic-fallback path only) --
__global__ __launch_bounds__(256) void hist_kernel(
    const int* __restrict__ idx, float* __restrict__ gcnt, int nrows)
{
    __shared__ uint32_t hh[NCLS];
    for (int i = threadIdx.x; i < NCLS; i += 256) hh[i] = 0u;
    __syncthreads();
    const int tid = blockIdx.x * 256 + threadIdx.x;
    const int stride = gridDim.x * 256;
    const int n4 = nrows >> 2;
    for (int i = tid; i < n4; i += stride) {
        int4 c = ((const int4*)idx)[i];
        atomicAdd(&hh[c.x], 1u); atomicAdd(&hh[c.y], 1u);
        atomicAdd(&hh[c.z], 1u); atomicAdd(&hh[c.w], 1u);
    }
    for (int i = (n4 << 2) + tid; i < nrows; i += stride)
        atomicAdd(&hh[idx[i]], 1u);
    __syncthreads();
    for (int i = threadIdx.x; i < NCLS; i += 256)
        if (hh[i]) global_fadd(&gcnt[i], (float)hh[i]);
}

// -------- Kernel 1c: reduce partials + counts hist, fused -----------------
// grid (50, 9): y<8 -> partial-sum slice over 96 blocks; y==8 -> idx hist
__global__ __launch_bounds__(256) void reduce_kernel(
    const float* __restrict__ part, const int* __restrict__ idx,
    float* __restrict__ gacc, int nrows)
{
    if (blockIdx.y == 8) {
        __shared__ uint32_t hh[NCLS];
        for (int i = threadIdx.x; i < NCLS; i += 256) hh[i] = 0u;
        __syncthreads();
        const int tid = blockIdx.x * 256 + threadIdx.x;
        const int stride = gridDim.x * 256;
        const int n4 = nrows >> 2;
        for (int i = tid; i < n4; i += stride) {
            int4 c = ((const int4*)idx)[i];
            atomicAdd(&hh[c.x], 1u); atomicAdd(&hh[c.y], 1u);
            atomicAdd(&hh[c.z], 1u); atomicAdd(&hh[c.w], 1u);
        }
        for (int i = (n4 << 2) + tid; i < nrows; i += stride)
            atomicAdd(&hh[idx[i]], 1u);
        __syncthreads();
        for (int i = threadIdx.x; i < NCLS; i += 256)
            if (hh[i]) global_fadd(&gacc[12800 + i], (float)hh[i]);
        return;
    }

    int pos = blockIdx.x * 256 + threadIdx.x;    // 0..12799
    if (pos >= PBLK) return;
    const int bq = G1 / 8;                       // 96
    int b0 = blockIdx.y * bq;

    const float* p = part + (size_t)b0 * PBLK + pos;
    float s0 = 0.f, s1 = 0.f, s2 = 0.f, s3 = 0.f;
    #pragma unroll 1
    for (int b = 0; b + 4 <= bq; b += 4) {
        s0 += p[(size_t)(b + 0) * PBLK];
        s1 += p[(size_t)(b + 1) * PBLK];
        s2 += p[(size_t)(b + 2) * PBLK];
        s3 += p[(size_t)(b + 3) * PBLK];
    }
    global_fadd(&gacc[pos], (s0 + s1) + (s2 + s3));
}

// ---------------- Kernel 2: finalize (unchanged, verified) ----------------
#define MSTR 68

__global__ __launch_bounds__(1024) void finalize_kernel(
    const float* __restrict__ gacc, float* __restrict__ out)
{
    __shared__ float mean_s[NCLS * MSTR];
    __shared__ float colstd[D];
    __shared__ float norms[NCLS];
    __shared__ float redSum[16], redMin[16];
    __shared__ float s_cov;

    const float* gSum = gacc;
    const float* gSq  = gacc + NCLS * D;
    const float* gCnt = gacc + 2 * NCLS * D;

    for (int d = threadIdx.x; d < D; d += 1024) colstd[d] = 0.0f;
    __syncthreads();

    for (int i = threadIdx.x; i < NCLS * D; i += 1024) {
        int c = i >> 6, d = i & 63;
        float cnt = gCnt[c];
        float m   = gSum[i] / cnt;
        float var = (gSq[i] - cnt * m * m) / (cnt - 1.0f);
        float sd  = sqrtf(fmaxf(var, 0.0f));
        mean_s[c * MSTR + d] = m;
        lds_fadd((uint32_t)(uintptr_t)(&colstd[d]), sd);
    }
    asm volatile("s_waitcnt lgkmcnt(0)" ::: "memory");
    __syncthreads();

    if (threadIdx.x < 64) {
        float v = colstd[threadIdx.x];
        v = v * v;
        for (int o = 32; o; o >>= 1) v += __shfl_down(v, o);
        if (threadIdx.x == 0) s_cov = v / (float)NCLS;
    }

    for (int c = threadIdx.x; c < NCLS; c += 1024) {
        const float4* mp = (const float4*)&mean_s[c * MSTR];
        float n = 0.0f;
        #pragma unroll
        for (int d4 = 0; d4 < D / 4; ++d4) {
            float4 a = mp[d4];
            n += a.x * a.x + a.y * a.y + a.z * a.z + a.w * a.w;
        }
        norms[c] = n;
    }
    __syncthreads();

    const int n_pairs = NCLS * (NCLS - 1) / 2;
    float lsum = 0.0f, lmin = INFINITY;
    for (int p = threadIdx.x; p < n_pairs; p += 1024) {
        int i = (int)((1.0f + sqrtf(1.0f + 8.0f * (float)p)) * 0.5f);
        while (i * (i - 1) / 2 > p) --i;
        while ((i + 1) * i / 2 <= p) ++i;
        int j = p - i * (i - 1) / 2;

        const float4* mi = (const float4*)&mean_s[i * MSTR];
        const float4* mj = (const float4*)&mean_s[j * MSTR];
        float dot = 0.0f;
        #pragma unroll
        for (int d4 = 0; d4 < D / 4; ++d4) {
            float4 a = mi[d4], b = mj[d4];
            dot += a.x * b.x + a.y * b.y + a.z * b.z + a.w * b.w;
        }
        float dist = norms[i] + norms[j] - 2.0f * dot;
        lsum += dist;
        lmin = fminf(lmin, dist);
    }

    for (int o = 32; o; o >>= 1) {
        lsum += __shfl_down(lsum, o);
        lmin = fminf(lmin, __shfl_down(lmin, o));
    }
    int ww = threadIdx.x >> 6;
    if ((threadIdx.x & 63) == 0) { redSum[ww] = lsum; redMin[ww] = lmin; }
    __syncthreads();

    if (threadIdx.x == 0) {
        float S = 0.0f, M = INFINITY;
        for (int k = 0; k < 16; ++k) { S += redSum[k]; M = fminf(M, redMin[k]); }
        float md  = S / (float)n_pairs;
        float cov = s_cov;
        float e   = 8.0f - md;
        float loss = 1.0f * cov + 0.1f * e * e;   // C_COEF = 0
        out[0] = loss;
        out[1] = md;
        out[2] = M;
        out[3] = cov;
    }
}

extern "C" void kernel_launch(void* const* d_in, const int* in_sizes, int n_in,
                              void* d_out, int out_size, void* d_ws, size_t ws_size,
                              hipStream_t stream) {
    const float* pred = (const float*)d_in[0];
    const int*   gidx = (const int*)d_in[1];
    float* out = (float*)d_out;
    int nrows = in_sizes[1];   // 2,000,000 rows

    const size_t partFloats = (size_t)G1 * PBLK;   // 9.83M floats = 39.3 MB

    if (ws_size >= (partFloats + GACC_FLOATS) * sizeof(float)) {
        float* part = (float*)d_ws;
        float* gacc = part + partFloats;
        hipMemsetAsync(gacc, 0, GACC_FLOATS * sizeof(float), stream);
        seg_mfma_kernel<<<G1, BLK, 0, stream>>>(pred, gidx, part, gacc, nrows, 0);
        dim3 gridR(PBLK / 256, 9);
        reduce_kernel<<<gridR, 256, 0, stream>>>(part, gidx, gacc, nrows);
        finalize_kernel<<<1, 1024, 0, stream>>>(gacc, out);
    } else {
        float* gacc = (float*)d_ws;
        hipMemsetAsync(gacc, 0, GACC_FLOATS * sizeof(float), stream);
        seg_mfma_kernel<<<G1, BLK, 0, stream>>>(pred, gidx, nullptr, gacc, nrows, 1);
        hist_kernel<<<1024, 256, 0, stream>>>(gidx, gacc + 12800, nrows);
        finalize_kernel<<<1, 1024, 0, stream>>>(gacc, out);
    }
}